// Round 1
// baseline (8684.549 us; speedup 1.0000x reference)
//
#include <hip/hip_runtime.h>
#include <cstddef>

#define HW 128
#define NPIX 16384  // 128*128

// out = relu(conv3x3(in, w) * g + b), pad=1.
// Input has 256 channels total: channels [0,cin1) from in1, [cin1,256) from in2
// (both laid out [B][cin_part][128][128]). Used for both init convs (cin1=256)
// and the cat conv (cin1=128, in1=x1_i, in2=x2_i).
__global__ __launch_bounds__(256) void conv3x3_bn_relu(
    const float* __restrict__ in1, const float* __restrict__ in2, int cin1,
    const float* __restrict__ w, const float* __restrict__ g, const float* __restrict__ bb,
    float* __restrict__ out, int co_total)
{
    __shared__ float xs[16 * 324];  // [ci_chunk=16][18*18] input tile + halo
    const int tid = threadIdx.x;
    const int tx = tid & 15, ty = tid >> 4;
    const int co0 = blockIdx.x * 16;        // co-group fastest -> L2 reuse of x tile
    const int tile = blockIdx.y;            // 64 spatial tiles of 16x16
    const int b = blockIdx.z;
    const int ty0 = (tile >> 3) * 16, tx0 = (tile & 7) * 16;
    const int h = ty0 + ty, wpix = tx0 + tx;
    const int cin2 = 256 - cin1;

    float acc[16];
#pragma unroll
    for (int i = 0; i < 16; ++i) acc[i] = 0.f;

    for (int cc = 0; cc < 16; ++cc) {       // 256 input channels in chunks of 16
        const int ci0 = cc * 16;
        __syncthreads();
        for (int idx = tid; idx < 16 * 324; idx += 256) {
            const int ci = idx / 324;
            const int rem = idx - ci * 324;
            const int r = rem / 18;
            const int c = rem - r * 18;
            const int gh = ty0 + r - 1, gw = tx0 + c - 1;
            float v = 0.f;
            if (gh >= 0 && gh < HW && gw >= 0 && gw < HW) {
                const int cig = ci0 + ci;
                const float* src = (cig < cin1)
                    ? in1 + ((size_t)b * cin1 + cig) * NPIX
                    : in2 + ((size_t)b * cin2 + (cig - cin1)) * NPIX;
                v = src[gh * HW + gw];
            }
            xs[idx] = v;
        }
        __syncthreads();
        for (int ci = 0; ci < 16; ++ci) {
            // weight base for (co0, ci0+ci); per-co stride = 256*9. Indices are
            // block-uniform -> compiler emits s_load (weights live in SGPRs).
            const float* wrow = w + ((size_t)co0 * 256 + (ci0 + ci)) * 9;
#pragma unroll
            for (int kh = 0; kh < 3; ++kh)
#pragma unroll
                for (int kw = 0; kw < 3; ++kw) {
                    const float xv = xs[ci * 324 + (ty + kh) * 18 + (tx + kw)];
#pragma unroll
                    for (int co = 0; co < 16; ++co)
                        acc[co] = fmaf(xv, wrow[(size_t)co * 2304 + kh * 3 + kw], acc[co]);
                }
        }
    }
#pragma unroll
    for (int co = 0; co < 16; ++co) {
        float v = acc[co] * g[co0 + co] + bb[co0 + co];
        v = v > 0.f ? v : 0.f;
        out[((size_t)b * co_total + co0 + co) * NPIX + h * HW + wpix] = v;
    }
}

// One wave per (head, window). lane = query pixel (8x8 window).
// Computes q,k,v for its own pixel from y1/y2 (1x1 conv, weights via s_load),
// shares k/v through LDS, two-pass online softmax of |q.k1 - q.k2|, writes
// o1 -> x1_i, o2 -> x2_i in [B][128][H][W] layout.
__global__ __launch_bounds__(64) void win_attn(
    const float* __restrict__ y1, const float* __restrict__ y2,
    const float* __restrict__ wq1, const float* __restrict__ bq1,
    const float* __restrict__ wk1, const float* __restrict__ bk1,
    const float* __restrict__ wv1, const float* __restrict__ bv1,
    const float* __restrict__ wq2, const float* __restrict__ bq2,
    const float* __restrict__ wk2, const float* __restrict__ bk2,
    const float* __restrict__ wv2, const float* __restrict__ bv2,
    float* __restrict__ x1i, float* __restrict__ x2i)
{
    const int n = blockIdx.x;        // head 0..7 (fastest -> same window adjacent in L2)
    const int wid = blockIdx.y;      // window 0..2047
    const int b = wid >> 8;
    const int wi = wid & 255;
    const int hy = wi >> 4, wx = wi & 15;
    const int p = threadIdx.x;       // query pixel 0..63
    const int iy = p >> 3, ix = p & 7;
    const int h = hy * 8 + iy, ww = wx * 8 + ix;
    const size_t pix = (size_t)h * HW + ww;

    const float* x1p = y1 + (size_t)b * 128 * NPIX + pix;
    const float* x2p = y2 + (size_t)b * 128 * NPIX + pix;

    float q1[4], q2[4], k1r[8], k2r[8], v1r[16], v2r[16];
#pragma unroll
    for (int d = 0; d < 4; ++d) { q1[d] = bq1[n * 4 + d]; q2[d] = bq2[n * 4 + d]; }
#pragma unroll
    for (int e = 0; e < 8; ++e) { k1r[e] = bk1[n * 8 + e]; k2r[e] = bk2[n * 8 + e]; }
#pragma unroll
    for (int f = 0; f < 16; ++f) { v1r[f] = bv1[n * 16 + f]; v2r[f] = bv2[n * 16 + f]; }

    for (int c = 0; c < 128; ++c) {
        const float xv1 = x1p[(size_t)c * NPIX];
        const float xv2 = x2p[(size_t)c * NPIX];
#pragma unroll
        for (int d = 0; d < 4; ++d) {
            q1[d] = fmaf(xv1, wq1[(n * 4 + d) * 128 + c], q1[d]);
            q2[d] = fmaf(xv2, wq2[(n * 4 + d) * 128 + c], q2[d]);
        }
#pragma unroll
        for (int e = 0; e < 8; ++e) {
            k1r[e] = fmaf(xv1, wk1[(n * 8 + e) * 128 + c], k1r[e]);
            k2r[e] = fmaf(xv2, wk2[(n * 8 + e) * 128 + c], k2r[e]);
        }
#pragma unroll
        for (int f = 0; f < 16; ++f) {
            v1r[f] = fmaf(xv1, wv1[(n * 16 + f) * 128 + c], v1r[f]);
            v2r[f] = fmaf(xv2, wv2[(n * 16 + f) * 128 + c], v2r[f]);
        }
    }

    // padded LDS: k stride 12 floats (48B, 16B-aligned rows), v stride 20 (80B)
    __shared__ __align__(16) float ks1[64][12];
    __shared__ __align__(16) float ks2[64][12];
    __shared__ __align__(16) float vs1[64][20];
    __shared__ __align__(16) float vs2[64][20];
#pragma unroll
    for (int e = 0; e < 8; ++e) { ks1[p][e] = k1r[e]; ks2[p][e] = k2r[e]; }
#pragma unroll
    for (int f = 0; f < 16; ++f) { vs1[p][f] = v1r[f]; vs2[p][f] = v2r[f]; }
    __syncthreads();

    // pass 1: row max of |s1 - s2|  (q_cat = [q1(4), q2(4)])
    float m = -1e30f;
    for (int kk = 0; kk < 64; ++kk) {
        float s1 = 0.f, s2 = 0.f;
#pragma unroll
        for (int d = 0; d < 4; ++d) {
            s1 = fmaf(q1[d], ks1[kk][d], s1);
            s2 = fmaf(q1[d], ks2[kk][d], s2);
        }
#pragma unroll
        for (int d = 0; d < 4; ++d) {
            s1 = fmaf(q2[d], ks1[kk][4 + d], s1);
            s2 = fmaf(q2[d], ks2[kk][4 + d], s2);
        }
        m = fmaxf(m, fabsf(s1 - s2));
    }

    // pass 2: recompute scores, accumulate unnormalized exp into o1/o2 and sum
    float o1[16], o2[16];
#pragma unroll
    for (int f = 0; f < 16; ++f) { o1[f] = 0.f; o2[f] = 0.f; }
    float sum = 0.f;
    for (int kk = 0; kk < 64; ++kk) {
        float s1 = 0.f, s2 = 0.f;
#pragma unroll
        for (int d = 0; d < 4; ++d) {
            s1 = fmaf(q1[d], ks1[kk][d], s1);
            s2 = fmaf(q1[d], ks2[kk][d], s2);
        }
#pragma unroll
        for (int d = 0; d < 4; ++d) {
            s1 = fmaf(q2[d], ks1[kk][4 + d], s1);
            s2 = fmaf(q2[d], ks2[kk][4 + d], s2);
        }
        const float e = __expf(fabsf(s1 - s2) - m);
        sum += e;
#pragma unroll
        for (int f = 0; f < 16; ++f) {
            o1[f] = fmaf(e, vs1[kk][f], o1[f]);
            o2[f] = fmaf(e, vs2[kk][f], o2[f]);
        }
    }
    const float inv = 1.f / sum;
    float* o1p = x1i + ((size_t)b * 128 + n * 16) * NPIX + pix;
    float* o2p = x2i + ((size_t)b * 128 + n * 16) * NPIX + pix;
#pragma unroll
    for (int f = 0; f < 16; ++f) {
        o1p[(size_t)f * NPIX] = o1[f] * inv;
        o2p[(size_t)f * NPIX] = o2[f] * inv;
    }
}

extern "C" void kernel_launch(void* const* d_in, const int* in_sizes, int n_in,
                              void* d_out, int out_size, void* d_ws, size_t ws_size,
                              hipStream_t stream) {
    const float* x1    = (const float*)d_in[0];
    const float* x2    = (const float*)d_in[1];
    const float* w_ic1 = (const float*)d_in[2];
    const float* g_ic1 = (const float*)d_in[3];
    const float* b_ic1 = (const float*)d_in[4];
    const float* w_ic2 = (const float*)d_in[5];
    const float* g_ic2 = (const float*)d_in[6];
    const float* b_ic2 = (const float*)d_in[7];
    const float* wq1   = (const float*)d_in[8];
    const float* bq1   = (const float*)d_in[9];
    const float* wk1   = (const float*)d_in[10];
    const float* bk1   = (const float*)d_in[11];
    const float* wv1   = (const float*)d_in[12];
    const float* bv1   = (const float*)d_in[13];
    const float* wq2   = (const float*)d_in[14];
    const float* bq2   = (const float*)d_in[15];
    const float* wk2   = (const float*)d_in[16];
    const float* bk2   = (const float*)d_in[17];
    const float* wv2   = (const float*)d_in[18];
    const float* bv2   = (const float*)d_in[19];
    const float* w_cat = (const float*)d_in[20];
    const float* g_cat = (const float*)d_in[21];
    const float* b_cat = (const float*)d_in[22];

    float* out = (float*)d_out;
    // d_out map (floats): [0, 33554432) x_cat | [33554432, 50331648) x1_i | [50331648, 67108864) x2_i
    // y1/y2 intermediates temporarily live in the x_cat region; K3 overwrites it last.
    float* y1   = out;
    float* y2   = out + 16777216;
    float* x1i  = out + 33554432;
    float* x2i  = out + 50331648;
    float* xcat = out;

    dim3 blk(256);
    // K1: two init convs (256 -> 128), BN+ReLU
    conv3x3_bn_relu<<<dim3(8, 64, 8), blk, 0, stream>>>(x1, x1, 256, w_ic1, g_ic1, b_ic1, y1, 128);
    conv3x3_bn_relu<<<dim3(8, 64, 8), blk, 0, stream>>>(x2, x2, 256, w_ic2, g_ic2, b_ic2, y2, 128);
    // K2: fused QKV + window attention + unwindow
    win_attn<<<dim3(8, 2048), dim3(64), 0, stream>>>(y1, y2,
        wq1, bq1, wk1, bk1, wv1, bv1,
        wq2, bq2, wk2, bk2, wv2, bv2,
        x1i, x2i);
    // K3: cat conv (128+128 -> 256), BN+ReLU (overwrites y1/y2 region)
    conv3x3_bn_relu<<<dim3(16, 64, 8), blk, 0, stream>>>(x1i, x2i, 128, w_cat, g_cat, b_cat, xcat, 256);
}

// Round 2
// 1997.273 us; speedup vs baseline: 4.3482x; 4.3482x over previous
//
#include <hip/hip_runtime.h>
#include <cstddef>

#define HW 128
#define NPIX 16384  // 128*128

typedef short short8 __attribute__((ext_vector_type(8)));
typedef float floatx4 __attribute__((ext_vector_type(4)));

static __device__ __forceinline__ unsigned short f2bf(float f) {
    unsigned int u = __float_as_uint(f);
    u += 0x7fffu + ((u >> 16) & 1u);
    return (unsigned short)(u >> 16);
}
static __device__ __forceinline__ float bf2f(unsigned short s) {
    return __uint_as_float(((unsigned int)s) << 16);
}

// wt[t][co][ci] = bf16(w[co][ci][kh][kw]), t = kh*3+kw. Tiny; runs every call.
__global__ __launch_bounds__(256) void prep_weights(
    const float* __restrict__ w, unsigned short* __restrict__ wt, int co_total)
{
    const int idx = blockIdx.x * 256 + threadIdx.x;
    const int total = co_total * 2304;
    if (idx >= total) return;
    const int per_t = co_total * 256;
    const int t = idx / per_t;
    const int rem = idx - t * per_t;
    const int co = rem >> 8;
    const int ci = rem & 255;
    wt[idx] = f2bf(w[(co * 256 + ci) * 9 + t]);
}

// Implicit-GEMM conv3x3 (pad=1) + BN(affine) + ReLU via bf16 MFMA.
// Tap decomposition: O[co][p] = sum_t W_t[co][ci] * X[ci][p_shift(t)].
// Block: 256 thr = 4 waves; output tile = 64 co x (16x16 px). Wave w: all 64 co
// of this co-block x 4 tile rows (orow0 = w*4). Per chunk: 32 ci staged in LDS
// pixel-major [324 px][32 ci] bf16 so b-frags are single ds_read_b128
// (B[k=ci][n=px], lane: n=lane&15, k=quad*8+j contiguous). a-frags are 16B
// global loads from wt[t][co][ci] (A[m=co][k=ci], lane: m=lane&15).
// C/D: col(=px)=lane&15, row(=co offset)=quad*4+reg.
__global__ __launch_bounds__(256, 2) void conv3x3_mfma(
    const float* __restrict__ in1, const float* __restrict__ in2, int cin1,
    const unsigned short* __restrict__ wt,
    const float* __restrict__ g, const float* __restrict__ bb,
    float* __restrict__ out_f, unsigned short* __restrict__ out_b, int co_total)
{
    __shared__ unsigned short xs[324 * 32];  // 20736 B
    const int tid = threadIdx.x;
    const int lane = tid & 63;
    const int wv = tid >> 6;        // wave 0..3
    const int px = lane & 15;       // MFMA m/n lane index
    const int quad = lane >> 4;     // MFMA k-quad
    const int cob = blockIdx.x;     // co-block of 64 (fastest -> L2 reuse of x tile)
    const int tile = blockIdx.y;    // 64 spatial tiles of 16x16
    const int b = blockIdx.z;
    const int ty0 = (tile >> 3) * 16, tx0 = (tile & 7) * 16;
    const int cin2 = 256 - cin1;
    const int orow0 = wv * 4;       // this wave's 4 tile rows

    floatx4 acc[4][4];              // [mg co-group][ng row] -> 64 regs
#pragma unroll
    for (int mg = 0; mg < 4; ++mg)
#pragma unroll
        for (int ng = 0; ng < 4; ++ng) acc[mg][ng] = (floatx4){0.f, 0.f, 0.f, 0.f};

    for (int ck = 0; ck < 8; ++ck) {
        const int ci0 = ck * 32;
        // ---- stage halo tile: (pix 0..323) x (q 0..3) -> 8 ci each, b128 write
        for (int it = tid; it < 1296; it += 256) {
            const int q = it & 3;
            const int pix = it >> 2;
            const int r = pix / 18;
            const int c = pix - r * 18;
            const int gh = ty0 + r - 1, gw = tx0 + c - 1;
            short8 sv;
            if (gh >= 0 && gh < HW && gw >= 0 && gw < HW) {
                const int off = gh * HW + gw;
#pragma unroll
                for (int i = 0; i < 8; ++i) {
                    const int cig = ci0 + q * 8 + i;
                    const float* src = (cig < cin1)
                        ? in1 + ((size_t)b * cin1 + cig) * NPIX
                        : in2 + ((size_t)b * cin2 + (cig - cin1)) * NPIX;
                    sv[i] = (short)f2bf(src[off]);
                }
            } else {
#pragma unroll
                for (int i = 0; i < 8; ++i) sv[i] = 0;
            }
            *(short8*)&xs[pix * 32 + q * 8] = sv;
        }
        __syncthreads();

        // ---- 9 taps x 16 MFMA, a/b frags reused 4x each
#pragma unroll
        for (int kh = 0; kh < 3; ++kh) {
#pragma unroll
            for (int kw = 0; kw < 3; ++kw) {
                const int t = kh * 3 + kw;
                short8 a[4], bf[4];
#pragma unroll
                for (int mg = 0; mg < 4; ++mg) {
                    const int co = cob * 64 + mg * 16 + px;
                    a[mg] = *(const short8*)(wt + (((size_t)(t * co_total + co)) << 8)
                                             + ci0 + quad * 8);
                }
#pragma unroll
                for (int ng = 0; ng < 4; ++ng) {
                    const int row = orow0 + ng + kh;
                    bf[ng] = *(const short8*)&xs[(row * 18 + px + kw) * 32 + quad * 8];
                }
#pragma unroll
                for (int mg = 0; mg < 4; ++mg)
#pragma unroll
                    for (int ng = 0; ng < 4; ++ng)
                        acc[mg][ng] = __builtin_amdgcn_mfma_f32_16x16x32_bf16(
                            a[mg], bf[ng], acc[mg][ng], 0, 0, 0);
            }
        }
        __syncthreads();
    }

    // ---- epilogue: BN affine + ReLU; write fp32 or bf16
#pragma unroll
    for (int mg = 0; mg < 4; ++mg) {
#pragma unroll
        for (int ng = 0; ng < 4; ++ng) {
            const int h = ty0 + orow0 + ng;
            const int wcol = tx0 + px;
#pragma unroll
            for (int r = 0; r < 4; ++r) {
                const int co = cob * 64 + mg * 16 + quad * 4 + r;
                float v = acc[mg][ng][r] * g[co] + bb[co];
                v = v > 0.f ? v : 0.f;
                const size_t idx = ((size_t)b * co_total + co) * NPIX + h * HW + wcol;
                if (out_b) out_b[idx] = f2bf(v);
                else out_f[idx] = v;
            }
        }
    }
}

// One wave per (head, window). lane = query pixel. y1/y2 are bf16 now.
__global__ __launch_bounds__(64) void win_attn(
    const unsigned short* __restrict__ y1, const unsigned short* __restrict__ y2,
    const float* __restrict__ wq1, const float* __restrict__ bq1,
    const float* __restrict__ wk1, const float* __restrict__ bk1,
    const float* __restrict__ wv1, const float* __restrict__ bv1,
    const float* __restrict__ wq2, const float* __restrict__ bq2,
    const float* __restrict__ wk2, const float* __restrict__ bk2,
    const float* __restrict__ wv2, const float* __restrict__ bv2,
    float* __restrict__ x1i, float* __restrict__ x2i)
{
    const int n = blockIdx.x;        // head
    const int wid = blockIdx.y;      // window
    const int b = wid >> 8;
    const int wi = wid & 255;
    const int hy = wi >> 4, wx = wi & 15;
    const int p = threadIdx.x;
    const int iy = p >> 3, ix = p & 7;
    const int h = hy * 8 + iy, ww = wx * 8 + ix;
    const size_t pix = (size_t)h * HW + ww;

    const unsigned short* x1p = y1 + (size_t)b * 128 * NPIX + pix;
    const unsigned short* x2p = y2 + (size_t)b * 128 * NPIX + pix;

    float q1[4], q2[4], k1r[8], k2r[8], v1r[16], v2r[16];
#pragma unroll
    for (int d = 0; d < 4; ++d) { q1[d] = bq1[n * 4 + d]; q2[d] = bq2[n * 4 + d]; }
#pragma unroll
    for (int e = 0; e < 8; ++e) { k1r[e] = bk1[n * 8 + e]; k2r[e] = bk2[n * 8 + e]; }
#pragma unroll
    for (int f = 0; f < 16; ++f) { v1r[f] = bv1[n * 16 + f]; v2r[f] = bv2[n * 16 + f]; }

    for (int c = 0; c < 128; ++c) {
        const float xv1 = bf2f(x1p[(size_t)c * NPIX]);
        const float xv2 = bf2f(x2p[(size_t)c * NPIX]);
#pragma unroll
        for (int d = 0; d < 4; ++d) {
            q1[d] = fmaf(xv1, wq1[(n * 4 + d) * 128 + c], q1[d]);
            q2[d] = fmaf(xv2, wq2[(n * 4 + d) * 128 + c], q2[d]);
        }
#pragma unroll
        for (int e = 0; e < 8; ++e) {
            k1r[e] = fmaf(xv1, wk1[(n * 8 + e) * 128 + c], k1r[e]);
            k2r[e] = fmaf(xv2, wk2[(n * 8 + e) * 128 + c], k2r[e]);
        }
#pragma unroll
        for (int f = 0; f < 16; ++f) {
            v1r[f] = fmaf(xv1, wv1[(n * 16 + f) * 128 + c], v1r[f]);
            v2r[f] = fmaf(xv2, wv2[(n * 16 + f) * 128 + c], v2r[f]);
        }
    }

    __shared__ __align__(16) float ks1[64][12];
    __shared__ __align__(16) float ks2[64][12];
    __shared__ __align__(16) float vs1[64][20];
    __shared__ __align__(16) float vs2[64][20];
#pragma unroll
    for (int e = 0; e < 8; ++e) { ks1[p][e] = k1r[e]; ks2[p][e] = k2r[e]; }
#pragma unroll
    for (int f = 0; f < 16; ++f) { vs1[p][f] = v1r[f]; vs2[p][f] = v2r[f]; }
    __syncthreads();

    float m = -1e30f;
    for (int kk = 0; kk < 64; ++kk) {
        float s1 = 0.f, s2 = 0.f;
#pragma unroll
        for (int d = 0; d < 4; ++d) {
            s1 = fmaf(q1[d], ks1[kk][d], s1);
            s2 = fmaf(q1[d], ks2[kk][d], s2);
        }
#pragma unroll
        for (int d = 0; d < 4; ++d) {
            s1 = fmaf(q2[d], ks1[kk][4 + d], s1);
            s2 = fmaf(q2[d], ks2[kk][4 + d], s2);
        }
        m = fmaxf(m, fabsf(s1 - s2));
    }

    float o1[16], o2[16];
#pragma unroll
    for (int f = 0; f < 16; ++f) { o1[f] = 0.f; o2[f] = 0.f; }
    float sum = 0.f;
    for (int kk = 0; kk < 64; ++kk) {
        float s1 = 0.f, s2 = 0.f;
#pragma unroll
        for (int d = 0; d < 4; ++d) {
            s1 = fmaf(q1[d], ks1[kk][d], s1);
            s2 = fmaf(q1[d], ks2[kk][d], s2);
        }
#pragma unroll
        for (int d = 0; d < 4; ++d) {
            s1 = fmaf(q2[d], ks1[kk][4 + d], s1);
            s2 = fmaf(q2[d], ks2[kk][4 + d], s2);
        }
        const float e = __expf(fabsf(s1 - s2) - m);
        sum += e;
#pragma unroll
        for (int f = 0; f < 16; ++f) {
            o1[f] = fmaf(e, vs1[kk][f], o1[f]);
            o2[f] = fmaf(e, vs2[kk][f], o2[f]);
        }
    }
    const float inv = 1.f / sum;
    float* o1p = x1i + ((size_t)b * 128 + n * 16) * NPIX + pix;
    float* o2p = x2i + ((size_t)b * 128 + n * 16) * NPIX + pix;
#pragma unroll
    for (int f = 0; f < 16; ++f) {
        o1p[(size_t)f * NPIX] = o1[f] * inv;
        o2p[(size_t)f * NPIX] = o2[f] * inv;
    }
}

extern "C" void kernel_launch(void* const* d_in, const int* in_sizes, int n_in,
                              void* d_out, int out_size, void* d_ws, size_t ws_size,
                              hipStream_t stream) {
    const float* x1    = (const float*)d_in[0];
    const float* x2    = (const float*)d_in[1];
    const float* w_ic1 = (const float*)d_in[2];
    const float* g_ic1 = (const float*)d_in[3];
    const float* b_ic1 = (const float*)d_in[4];
    const float* w_ic2 = (const float*)d_in[5];
    const float* g_ic2 = (const float*)d_in[6];
    const float* b_ic2 = (const float*)d_in[7];
    const float* wq1   = (const float*)d_in[8];
    const float* bq1   = (const float*)d_in[9];
    const float* wk1   = (const float*)d_in[10];
    const float* bk1   = (const float*)d_in[11];
    const float* wv1   = (const float*)d_in[12];
    const float* bv1   = (const float*)d_in[13];
    const float* wq2   = (const float*)d_in[14];
    const float* bq2   = (const float*)d_in[15];
    const float* wk2   = (const float*)d_in[16];
    const float* bk2   = (const float*)d_in[17];
    const float* wv2   = (const float*)d_in[18];
    const float* bv2   = (const float*)d_in[19];
    const float* w_cat = (const float*)d_in[20];
    const float* g_cat = (const float*)d_in[21];
    const float* b_cat = (const float*)d_in[22];

    float* out = (float*)d_out;
    // d_out map (floats): [0, 33.5M) x_cat | [33.5M, 50.3M) x1_i | [50.3M, 67.1M) x2_i
    // bf16 y1/y2 live in the x_cat region (67 MB of its 134 MB); K3 overwrites last.
    unsigned short* y1b = (unsigned short*)d_out;
    unsigned short* y2b = y1b + 16777216;
    float* x1i  = out + 33554432;
    float* x2i  = out + 50331648;
    float* xcat = out;

    // d_ws: transformed bf16 weights [tap][co][ci]
    unsigned short* wt_ic1 = (unsigned short*)d_ws;
    unsigned short* wt_ic2 = wt_ic1 + 294912;   // 128*256*9
    unsigned short* wt_cat = wt_ic2 + 294912;   // 256*256*9 = 589824

    prep_weights<<<dim3(1152), dim3(256), 0, stream>>>(w_ic1, wt_ic1, 128);
    prep_weights<<<dim3(1152), dim3(256), 0, stream>>>(w_ic2, wt_ic2, 128);
    prep_weights<<<dim3(2304), dim3(256), 0, stream>>>(w_cat, wt_cat, 256);

    // K1: init convs (256 -> 128), bf16 out
    conv3x3_mfma<<<dim3(2, 64, 8), dim3(256), 0, stream>>>(
        x1, x1, 256, wt_ic1, g_ic1, b_ic1, nullptr, y1b, 128);
    conv3x3_mfma<<<dim3(2, 64, 8), dim3(256), 0, stream>>>(
        x2, x2, 256, wt_ic2, g_ic2, b_ic2, nullptr, y2b, 128);
    // K2: fused QKV + window attention
    win_attn<<<dim3(8, 2048), dim3(64), 0, stream>>>(y1b, y2b,
        wq1, bq1, wk1, bk1, wv1, bv1,
        wq2, bq2, wk2, bk2, wv2, bv2,
        x1i, x2i);
    // K3: cat conv (128+128 -> 256), fp32 out (overwrites y region)
    conv3x3_mfma<<<dim3(4, 64, 8), dim3(256), 0, stream>>>(
        x1i, x2i, 128, wt_cat, g_cat, b_cat, xcat, nullptr, 256);
}